// Round 14
// baseline (98.460 us; speedup 1.0000x reference)
//
#include <hip/hip_runtime.h>
#include <hip/hip_bf16.h>
#include <hip/hip_fp16.h>

// Problem constants
#define BB 2048
#define NN 100
#define INF_ 64
#define HH 256
#define CC 3
#define NET 19   // edge tiles of 16 (300 edges -> 19 tiles)

typedef __attribute__((ext_vector_type(8))) _Float16 h8v;  // 8 fp16 (4 VGPRs)
typedef __attribute__((ext_vector_type(2))) __fp16   g2v;  // builtin ABI pair
typedef __attribute__((ext_vector_type(4))) float f4v;     // 4 fp32 acc

// pack 2 f32 -> packed fp16 (RTZ, single v_cvt_pkrtz_f16_f32)
static __device__ __forceinline__ unsigned int pkh(float lo, float hi) {
    union { g2v g; unsigned int u; } c;
    c.g = __builtin_amdgcn_cvt_pkrtz(lo, hi);
    return c.u;
}

// ---------------------------------------------------------------------------
// Kernel P: Wcomb[z][64][256] = W_exp @ W_{l,r}[2] (f32)
//           cadd[z][100][256] = (b_exp + pe[n]) @ W_{l,r}[2] + b_{l,r}[2] (f32)
// ---------------------------------------------------------------------------
__global__ __launch_bounds__(256) void precompute_k(
    const float* __restrict__ W_exp, const float* __restrict__ b_exp,
    const float* __restrict__ W_l, const float* __restrict__ b_l,
    const float* __restrict__ W_r, const float* __restrict__ b_r,
    float* __restrict__ Wcomb, float* __restrict__ cadd)
{
    int r = blockIdx.x;           // 0..163
    int z = blockIdx.y;           // 0 = l, 1 = r
    int t = threadIdx.x;          // output col
    const float* Wg = (z ? W_r : W_l) + 2 * HH * HH;  // layer 2
    const float* bg = (z ? b_r : b_l) + 2 * HH;

    __shared__ float sa[HH];
    float a;
    if (r < INF_) {
        a = W_exp[r * HH + t];
    } else {
        int n = r - INF_;
        float div = expf((float)(t & 254) * (-0.03597789207803f));
        float ang = (float)n * div;
        a = b_exp[t] + ((t & 1) ? cosf(ang) : sinf(ang));
    }
    sa[t] = a;
    __syncthreads();

    float acc = 0.f;
    #pragma unroll 8
    for (int h = 0; h < HH; ++h)
        acc += sa[h] * Wg[h * HH + t];

    if (r < INF_) Wcomb[(z * INF_ + r) * HH + t] = acc;
    else          cadd[(z * NN + (r - INF_)) * HH + t] = acc + bg[t];
}

// ---------------------------------------------------------------------------
// Kernel R: rearrange into MFMA fragment layouts.
//  WF (fp16) [z][nt:16][ks:2][lane:64][j:8] : Wcomb[z][k][n],
//      k = ks*32 + 4*(lane>>4) + (j&3) + 16*(j>>2),  n = nt*16 + (lane&15)
//    (doubles as W' = [Wcomb_l; Wcomb_r] frags: ksf = z*2+ks)
//  CFE (f32) [et:19][nt:16][lane:64][r:4] : cadd_l[src]+cadd_r[dst] at
//      edge = et*16 + (lane&15) (clamped), feat = nt*16 + (lane>>4)*4 + r
//    (matches swapped-operand D layout: col=edge, row=feat)
// ---------------------------------------------------------------------------
#define N_WF 32768
#define N_CFE4 19456   // 19*16*64 float4 slots

__global__ __launch_bounds__(256) void rearrange_k(
    const float* __restrict__ Wcomb, const float* __restrict__ cadd,
    unsigned short* __restrict__ WF, float* __restrict__ CFE)
{
    int i = blockIdx.x * 256 + threadIdx.x;
    if (i < N_WF) {
        int j = i & 7, lane = (i >> 3) & 63, ks = (i >> 9) & 1;
        int nt = (i >> 10) & 15, z = (i >> 14) & 1;
        int k = ks * 32 + 4 * (lane >> 4) + (j & 3) + 16 * (j >> 2);
        int n = nt * 16 + (lane & 15);
        __half h = __float2half(Wcomb[(z * INF_ + k) * HH + n]);   // RNE
        WF[i] = __half_as_ushort(h);
    } else if (i < N_WF + N_CFE4) {
        int i2 = i - N_WF;
        int lane = i2 & 63, nt = (i2 >> 6) & 15, et = i2 >> 10;   // et 0..18
        int edge = et * 16 + (lane & 15);
        if (edge > 299) edge = 299;
        int src = edge / 3;
        int dst = src + (edge - 3 * src) - 1;
        dst = dst < 0 ? 0 : (dst > NN - 1 ? NN - 1 : dst);
        int feat = nt * 16 + (lane >> 4) * 4;
        float4 a = *(const float4*)&cadd[(0 * NN + src) * HH + feat];
        float4 b = *(const float4*)&cadd[(1 * NN + dst) * HH + feat];
        float4 v = { a.x + b.x, a.y + b.y, a.z + b.z, a.w + b.w };
        *(float4*)&CFE[(size_t)i2 * 4] = v;
    }
}

// ---------------------------------------------------------------------------
// Kernel F (fused): one block per batch, 512 threads (8 waves).
//  Stage x[b] -> LDS fp16 node-frags (sxs, read-only afterwards).
//  BARRIER-FREE main loop: wave w owns feat tiles nt0=2w, nt0+1. Per edge
//  tile et (19): gather 4 E-frags from sxs (per-lane LDS addressing),
//  CFE C-init (L2), 8 MFMA -> lane holds 8 feats of ONE edge in f32 ->
//  factored leaky dot (sv, sa) in registers -> shfl_xor(16,32) -> spart.
//  xl/xr are NEVER materialized. Cross-wave feat reduce -> lg; softmax ->
//  wv; pooled ALGEBRAIC: (wv@x)@Wcomb_l + wv@cadd_l + 100*bias; FC.
//  LDS = 14336 (sxs; tail scratch aliases) + 9728 (spart) = 24064 B.
// ---------------------------------------------------------------------------
__global__ __launch_bounds__(512, 4) void fused_k(
    const float* __restrict__ x,
    const unsigned short* __restrict__ WF, const float* __restrict__ CFE,
    const float* __restrict__ Wcomb, const float* __restrict__ cadd,
    const float* __restrict__ att, const float* __restrict__ bias,
    const float* __restrict__ Wfc, const float* __restrict__ bfc,
    float* __restrict__ out)
{
    __shared__ unsigned short sxs[896 * 8];    // 14336 B node frags; later scratch
    __shared__ float spart[8][304];            // 9728 B per-wave logit partials

    int b = blockIdx.x, t = threadIdx.x;
    int wave = t >> 6, lane = t & 63, g = lane >> 4, li = lane & 15;

    // ---- stage x[b] as fp16 node fragments ----
    const float* xb = x + (size_t)b * (NN * INF_);
    for (int s = t; s < 896; s += 512) {
        int sl = s & 63, ks = (s >> 6) & 1, mt = s >> 7;
        int m = mt * 16 + (sl & 15), gg = sl >> 4;
        union { h8v v; unsigned int u[4]; } a;
        if (m < NN) {
            float4 u = *(const float4*)&xb[m * INF_ + ks * 32 + 4 * gg];
            float4 v = *(const float4*)&xb[m * INF_ + ks * 32 + 16 + 4 * gg];
            a.u[0] = pkh(u.x, u.y);
            a.u[1] = pkh(u.z, u.w);
            a.u[2] = pkh(v.x, v.y);
            a.u[3] = pkh(v.z, v.w);
        } else {
            a.u[0] = a.u[1] = a.u[2] = a.u[3] = 0u;
        }
        *(h8v*)&sxs[s * 8] = a.v;
    }

    // ---- hoist W' frags + att for this wave's two feat tiles ----
    int nt0 = wave * 2;
    const h8v* WFp = (const h8v*)WF;
    // ksf = z*2+ks: index (((ksf>>1)*16 + nt)*2 + (ksf&1))*64 + lane
    h8v wA0 = WFp[((0 * 16 + nt0) * 2 + 0) * 64 + lane];
    h8v wA1 = WFp[((0 * 16 + nt0) * 2 + 1) * 64 + lane];
    h8v wA2 = WFp[((1 * 16 + nt0) * 2 + 0) * 64 + lane];
    h8v wA3 = WFp[((1 * 16 + nt0) * 2 + 1) * 64 + lane];
    h8v wB0 = WFp[((0 * 16 + nt0 + 1) * 2 + 0) * 64 + lane];
    h8v wB1 = WFp[((0 * 16 + nt0 + 1) * 2 + 1) * 64 + lane];
    h8v wB2 = WFp[((1 * 16 + nt0 + 1) * 2 + 0) * 64 + lane];
    h8v wB3 = WFp[((1 * 16 + nt0 + 1) * 2 + 1) * 64 + lane];
    f4v aA = *(const f4v*)&att[2 * HH + nt0 * 16 + g * 4];
    f4v aB = *(const f4v*)&att[2 * HH + (nt0 + 1) * 16 + g * 4];

    __syncthreads();                           // sxs ready

    const h8v* sp = (const h8v*)sxs;
    const f4v* CFE4 = (const f4v*)CFE;

    // ---- barrier-free edge-GEMM + in-register logits ----
    for (int et = 0; et < NET; ++et) {
        int edge = et * 16 + li;
        bool eok = (edge < 300);
        int ec = eok ? edge : 299;
        int src = ec / 3;
        int dst = src + (ec - 3 * src) - 1;
        int dstc = dst < 0 ? 0 : (dst > NN - 1 ? NN - 1 : dst);
        int slotS = (src >> 4) * 128 + g * 16 + (src & 15);
        int slotD = (dstc >> 4) * 128 + g * 16 + (dstc & 15);
        h8v e0 = sp[slotS];            // x[src], k 0..31
        h8v e1 = sp[slotS + 64];       // x[src], k 32..63
        h8v e2 = sp[slotD];            // x[dst], k 0..31
        h8v e3 = sp[slotD + 64];       // x[dst], k 32..63

        f4v c0 = CFE4[(et * 16 + nt0) * 64 + lane];
        f4v c1 = CFE4[(et * 16 + nt0 + 1) * 64 + lane];
        c0 = __builtin_amdgcn_mfma_f32_16x16x32_f16(wA0, e0, c0, 0, 0, 0);
        c1 = __builtin_amdgcn_mfma_f32_16x16x32_f16(wB0, e0, c1, 0, 0, 0);
        c0 = __builtin_amdgcn_mfma_f32_16x16x32_f16(wA1, e1, c0, 0, 0, 0);
        c1 = __builtin_amdgcn_mfma_f32_16x16x32_f16(wB1, e1, c1, 0, 0, 0);
        c0 = __builtin_amdgcn_mfma_f32_16x16x32_f16(wA2, e2, c0, 0, 0, 0);
        c1 = __builtin_amdgcn_mfma_f32_16x16x32_f16(wB2, e2, c1, 0, 0, 0);
        c0 = __builtin_amdgcn_mfma_f32_16x16x32_f16(wA3, e3, c0, 0, 0, 0);
        c1 = __builtin_amdgcn_mfma_f32_16x16x32_f16(wB3, e3, c1, 0, 0, 0);

        // factored leaky dot: lg += att*(0.6 v + 0.4|v|) = 0.6 sv + 0.4 sa
        float sv = 0.f, sa = 0.f;
        #pragma unroll
        for (int r = 0; r < 4; ++r) {
            float v0 = c0[r];
            sv = fmaf(aA[r], v0, sv); sa = fmaf(aA[r], fabsf(v0), sa);
            float v1 = c1[r];
            sv = fmaf(aB[r], v1, sv); sa = fmaf(aB[r], fabsf(v1), sa);
        }
        float s = fmaf(0.6f, sv, 0.4f * sa);
        s += __shfl_xor(s, 16, 64);
        s += __shfl_xor(s, 32, 64);            // all 4 feat-groups combined
        if (lane < 16 && eok)
            spart[wave][et * 16 + lane] = s;
    }
    __syncthreads();                           // spart complete, sxs dead

    // scratch aliases sxs
    float* lg      = (float*)sxs;          // 304 floats
    float* wvp     = lg + 304;             // 100 floats
    float* partial = wvp + 108;            // 12 floats
    float* ypart   = partial + 16;         // 8*64 floats

    if (t < 300) {
        float s = 0.f;
        #pragma unroll
        for (int w = 0; w < 8; ++w) s += spart[w][t];
        lg[t] = s;    // edges 0 and 299 are garbage-but-finite, never read
    }
    __syncthreads();

    // ---- wv[i] = sum over dst j in {i-1,i,i+1} of alpha(i->j) ----
    if (t < NN) {
        int i = t;
        float w = 0.f;
        #pragma unroll
        for (int dj = -1; dj <= 1; ++dj) {
            int j = i + dj;
            if (j < 0 || j >= NN) continue;
            float l0 = (j - 1 >= 0) ? lg[3 * (j - 1) + 2] : -1e30f;  // j-1 -> j
            float l1 = lg[3 * j + 1];                                 // j   -> j
            float l2 = (j + 1 < NN) ? lg[3 * (j + 1) + 0] : -1e30f;  // j+1 -> j
            float mx = fmaxf(fmaxf(l0, l1), l2);
            float den = expf(l0 - mx) + expf(l1 - mx) + expf(l2 - mx);
            float myl = lg[3 * i + dj + 1];
            w += expf(myl - mx) / den;
        }
        wvp[i] = w;
    }
    __syncthreads();

    // ---- y[k] = sum_i wv[i] * x[b][i][k]  (k < 64), per-wave row chunks ----
    {
        int r0 = wave * 13;
        int r1 = (r0 + 13 < NN) ? r0 + 13 : NN;
        float acc = 0.f;
        for (int i = r0; i < r1; ++i)
            acc = fmaf(wvp[i], xb[i * INF_ + lane], acc);
        ypart[wave * 64 + lane] = acc;
    }
    __syncthreads();
    if (t < 64) {
        float s = 0.f;
        #pragma unroll
        for (int w = 0; w < 8; ++w) s += ypart[w * 64 + t];
        ypart[t] = s;                       // y[k]
    }
    __syncthreads();

    // ---- pooled[f] = y @ Wcomb_l[:,f] + wv @ cadd_l[:,f] + 100*bias[f]; FC ----
    if (t < HH) {
        float p = 100.f * bias[2 * HH + t];
        #pragma unroll
        for (int k = 0; k < INF_; k += 4) {
            float4 y4 = *(const float4*)&ypart[k];
            p = fmaf(y4.x, Wcomb[(k + 0) * HH + t], p);
            p = fmaf(y4.y, Wcomb[(k + 1) * HH + t], p);
            p = fmaf(y4.z, Wcomb[(k + 2) * HH + t], p);
            p = fmaf(y4.w, Wcomb[(k + 3) * HH + t], p);
        }
        #pragma unroll
        for (int i = 0; i < NN; i += 4) {
            float4 w4v = *(const float4*)&wvp[i];
            p = fmaf(w4v.x, cadd[(i + 0) * HH + t], p);
            p = fmaf(w4v.y, cadd[(i + 1) * HH + t], p);
            p = fmaf(w4v.z, cadd[(i + 2) * HH + t], p);
            p = fmaf(w4v.w, cadd[(i + 3) * HH + t], p);
        }

        float p0 = p * Wfc[t * 3 + 0];
        float p1 = p * Wfc[t * 3 + 1];
        float p2 = p * Wfc[t * 3 + 2];
        #pragma unroll
        for (int off = 32; off; off >>= 1) {
            p0 += __shfl_down(p0, off, 64);
            p1 += __shfl_down(p1, off, 64);
            p2 += __shfl_down(p2, off, 64);
        }
        if (lane == 0) {
            partial[wave * 3 + 0] = p0;
            partial[wave * 3 + 1] = p1;
            partial[wave * 3 + 2] = p2;
        }
    }
    __syncthreads();
    if (t < CC) {
        out[(size_t)b * CC + t] =
            partial[0 * 3 + t] + partial[1 * 3 + t] +
            partial[2 * 3 + t] + partial[3 * 3 + t] + bfc[t];
    }
}

// ---------------------------------------------------------------------------
extern "C" void kernel_launch(void* const* d_in, const int* in_sizes, int n_in,
                              void* d_out, int out_size, void* d_ws, size_t ws_size,
                              hipStream_t stream) {
    const float* x     = (const float*)d_in[0];
    const float* W_exp = (const float*)d_in[1];
    const float* b_exp = (const float*)d_in[2];
    const float* W_l   = (const float*)d_in[3];
    const float* b_l   = (const float*)d_in[4];
    const float* W_r   = (const float*)d_in[5];
    const float* b_r   = (const float*)d_in[6];
    const float* att   = (const float*)d_in[7];
    const float* bias  = (const float*)d_in[8];
    const float* W_fc  = (const float*)d_in[9];
    const float* b_fc  = (const float*)d_in[10];
    float* out = (float*)d_out;

    // workspace layout (16B aligned)
    char* ws = (char*)d_ws;
    float* Wcomb = (float*)ws;                                     // 131072 B
    float* cadd  = (float*)(ws + 131072);                          // 204800 B
    unsigned short* WF = (unsigned short*)(ws + 131072 + 204800);  // 65536 B
    float* CFE = (float*)(ws + 131072 + 204800 + 65536);           // 311296 B

    precompute_k<<<dim3(164, 2), 256, 0, stream>>>(W_exp, b_exp, W_l, b_l, W_r, b_r,
                                                   Wcomb, cadd);
    rearrange_k<<<204, 256, 0, stream>>>(Wcomb, cadd, WF, CFE);
    fused_k<<<BB, 512, 0, stream>>>(x, WF, CFE, Wcomb, cadd, att, bias, W_fc, b_fc, out);
}

// Round 17
// 88.161 us; speedup vs baseline: 1.1168x; 1.1168x over previous
//
#include <hip/hip_runtime.h>
#include <hip/hip_bf16.h>
#include <hip/hip_fp16.h>

// Problem constants
#define BB 2048
#define NN 100
#define INF_ 64
#define HH 256
#define CC 3

typedef __attribute__((ext_vector_type(8))) _Float16 h8v;  // 8 fp16 (4 VGPRs)
typedef __attribute__((ext_vector_type(2))) __fp16   g2v;  // builtin ABI pair
typedef __attribute__((ext_vector_type(4))) float f4v;     // 4 fp32 acc

// pack 2 f32 -> packed fp16 (RTZ, single v_cvt_pkrtz_f16_f32)
static __device__ __forceinline__ unsigned int pkh(float lo, float hi) {
    union { g2v g; unsigned int u; } c;
    c.g = __builtin_amdgcn_cvt_pkrtz(lo, hi);
    return c.u;
}
// neighbor exchange via shfl (R14-proven on MFMA-derived values)
static __device__ __forceinline__ float lane_m1(float v) {  // lane i <- i-1
    return __shfl_up(v, 1, 64);
}
static __device__ __forceinline__ float lane_p1(float v) {  // lane i <- i+1
    return __shfl_down(v, 1, 64);
}

// ---------------------------------------------------------------------------
// Kernel P: Wcomb[z][64][256] = W_exp @ W_{l,r}[2] (f32)
//           cadd[z][100][256] = (b_exp + pe[n]) @ W_{l,r}[2] + b_{l,r}[2] (f32)
// ---------------------------------------------------------------------------
__global__ __launch_bounds__(256) void precompute_k(
    const float* __restrict__ W_exp, const float* __restrict__ b_exp,
    const float* __restrict__ W_l, const float* __restrict__ b_l,
    const float* __restrict__ W_r, const float* __restrict__ b_r,
    float* __restrict__ Wcomb, float* __restrict__ cadd)
{
    int r = blockIdx.x;           // 0..163
    int z = blockIdx.y;           // 0 = l, 1 = r
    int t = threadIdx.x;          // output col
    const float* Wg = (z ? W_r : W_l) + 2 * HH * HH;  // layer 2
    const float* bg = (z ? b_r : b_l) + 2 * HH;

    __shared__ float sa[HH];
    float a;
    if (r < INF_) {
        a = W_exp[r * HH + t];
    } else {
        int n = r - INF_;
        float div = expf((float)(t & 254) * (-0.03597789207803f));
        float ang = (float)n * div;
        a = b_exp[t] + ((t & 1) ? cosf(ang) : sinf(ang));
    }
    sa[t] = a;
    __syncthreads();

    float acc = 0.f;
    #pragma unroll 8
    for (int h = 0; h < HH; ++h)
        acc += sa[h] * Wg[h * HH + t];

    if (r < INF_) Wcomb[(z * INF_ + r) * HH + t] = acc;
    else          cadd[(z * NN + (r - INF_)) * HH + t] = acc + bg[t];
}

// ---------------------------------------------------------------------------
// Kernel R: rearrange into MFMA fragment layouts (fp16 weights, f32 C-init).
//  WF (fp16) [z][nt:16][ks:2][lane:64][j:8] : Wcomb[z][k][n],
//      k = ks*32 + 4*(lane>>4) + (j&3) + 16*(j>>2),  n = nt*16 + (lane&15)
//  CFf (f32) [z][mt:7][nt:16][lane:64][r:4] : cadd[z][node][feat],
//      node = mt*16 + (lane&15), feat = nt*16 + (lane>>4)*4 + r  (node>=100 -> 0)
// ---------------------------------------------------------------------------
#define N_WF 32768
#define N_CF4 14336   // float4 slots

__global__ __launch_bounds__(256) void rearrange_k(
    const float* __restrict__ Wcomb, const float* __restrict__ cadd,
    unsigned short* __restrict__ WF, float* __restrict__ CFf)
{
    int i = blockIdx.x * 256 + threadIdx.x;
    if (i < N_WF) {
        int j = i & 7, lane = (i >> 3) & 63, ks = (i >> 9) & 1;
        int nt = (i >> 10) & 15, z = (i >> 14) & 1;
        int k = ks * 32 + 4 * (lane >> 4) + (j & 3) + 16 * (j >> 2);
        int n = nt * 16 + (lane & 15);
        __half h = __float2half(Wcomb[(z * INF_ + k) * HH + n]);   // RNE
        WF[i] = __half_as_ushort(h);
    } else if (i < N_WF + N_CF4) {
        int i2 = i - N_WF;
        int lane = i2 & 63, nt = (i2 >> 6) & 15;
        int zm = i2 >> 10;                 // 0..13
        int mt = zm % 7, z = zm / 7;
        int node = mt * 16 + (lane & 15);
        int feat = nt * 16 + (lane >> 4) * 4;
        float4 v = {0.f, 0.f, 0.f, 0.f};
        if (node < NN)
            v = *(const float4*)&cadd[(z * NN + node) * HH + feat];
        *(float4*)&CFf[(size_t)i2 * 4] = v;
    }
}

// ---------------------------------------------------------------------------
// Kernel F (fused): one block per batch, 512 threads (8 waves).
//  Stage x[b] -> LDS fp16 node-frags (sxs, read-only after).
//  BARRIER-FREE main loop over mt: wave owns feat tiles {2w, 2w+1}; computes
//  cl (xl) AND cr (xr) for its 16 nodes x 8 feats in f32 regs (CFf C-init);
//  chain neighbors via __shfl_up/down; att-dot with factored leaky;
//  CROSS-G-GROUP shfl_xor(16,32) reduction (the R15/R16 bug: 4 g-lanes hold
//  the same node's feats and must be summed BEFORE the spart store) ->
//  spart[wave] from lanes<16. Boundary edges (12) via mini edge-GEMM.
//  Reduce 8 waves -> lg; softmax -> wv; pooled ALGEBRAIC; FC.
//  LDS = 14336 (sxs, tail scratch aliases) + 9728 (spart) + 512 (spartB).
// ---------------------------------------------------------------------------
__global__ __launch_bounds__(512, 4) void fused_k(
    const float* __restrict__ x,
    const unsigned short* __restrict__ WF, const float* __restrict__ CFf,
    const float* __restrict__ Wcomb, const float* __restrict__ cadd,
    const float* __restrict__ att, const float* __restrict__ bias,
    const float* __restrict__ Wfc, const float* __restrict__ bfc,
    float* __restrict__ out)
{
    __shared__ unsigned short sxs[896 * 8];   // 14336 B node frags; later scratch
    __shared__ float spart[8][304];           // 9728 B per-wave edge partials
    __shared__ float spartB[8][16];           // 512 B boundary-edge partials

    int b = blockIdx.x, t = threadIdx.x;
    int wave = t >> 6, lane = t & 63, g = lane >> 4, li = lane & 15;

    // ---- stage x[b] as fp16 node fragments ----
    const float* xb = x + (size_t)b * (NN * INF_);
    for (int s = t; s < 896; s += 512) {
        int sl = s & 63, ks = (s >> 6) & 1, mt = s >> 7;
        int m = mt * 16 + (sl & 15), gg = sl >> 4;
        union { h8v v; unsigned int u[4]; } a;
        if (m < NN) {
            float4 u = *(const float4*)&xb[m * INF_ + ks * 32 + 4 * gg];
            float4 v = *(const float4*)&xb[m * INF_ + ks * 32 + 16 + 4 * gg];
            a.u[0] = pkh(u.x, u.y);
            a.u[1] = pkh(u.z, u.w);
            a.u[2] = pkh(v.x, v.y);
            a.u[3] = pkh(v.z, v.w);
        } else {
            a.u[0] = a.u[1] = a.u[2] = a.u[3] = 0u;
        }
        *(h8v*)&sxs[s * 8] = a.v;
    }

    // ---- hoist weight frags + att for this wave's two feat tiles ----
    int nt0 = wave * 2;
    const h8v* WFp = (const h8v*)WF;
    h8v wf[2][2][2];   // [j][z][ks], all statically indexed under unroll
    #pragma unroll
    for (int j = 0; j < 2; ++j)
        #pragma unroll
        for (int z = 0; z < 2; ++z)
            #pragma unroll
            for (int ks = 0; ks < 2; ++ks)
                wf[j][z][ks] = WFp[((z * 16 + nt0 + j) * 2 + ks) * 64 + lane];
    f4v aA = *(const f4v*)&att[2 * HH + nt0 * 16 + g * 4];
    f4v aB = *(const f4v*)&att[2 * HH + (nt0 + 1) * 16 + g * 4];

    __syncthreads();                          // sxs ready

    const h8v* sp = (const h8v*)sxs;
    const f4v* CF4 = (const f4v*)CFf;

    // ---- barrier-free main loop: per mt, in-register edge logits ----
    #pragma unroll
    for (int mt = 0; mt < 7; ++mt) {
        h8v a0 = sp[mt * 128 + lane];         // shared by all 4 weight jobs
        h8v a1 = sp[mt * 128 + 64 + lane];
        float sv0 = 0.f, sv1 = 0.f, sv2 = 0.f;
        float sa0 = 0.f, sa1 = 0.f, sa2 = 0.f;
        #pragma unroll
        for (int j = 0; j < 2; ++j) {
            int nt = nt0 + j;
            f4v cl = CF4[((0 * 7 + mt) * 16 + nt) * 64 + lane];
            f4v cr = CF4[((1 * 7 + mt) * 16 + nt) * 64 + lane];
            cl = __builtin_amdgcn_mfma_f32_16x16x32_f16(wf[j][0][0], a0, cl, 0, 0, 0);
            cl = __builtin_amdgcn_mfma_f32_16x16x32_f16(wf[j][0][1], a1, cl, 0, 0, 0);
            cr = __builtin_amdgcn_mfma_f32_16x16x32_f16(wf[j][1][0], a0, cr, 0, 0, 0);
            cr = __builtin_amdgcn_mfma_f32_16x16x32_f16(wf[j][1][1], a1, cr, 0, 0, 0);
            f4v at = j ? aB : aA;
            #pragma unroll
            for (int r = 0; r < 4; ++r) {
                float crm = lane_m1(cr[r]);    // xr[node-1]
                float crp = lane_p1(cr[r]);    // xr[node+1]
                float v1 = cl[r] + cr[r];      // self edge
                float vm = cl[r] + crm;        // edge node -> node-1
                float vp = cl[r] + crp;        // edge node -> node+1
                sv1 = fmaf(at[r], v1, sv1); sa1 = fmaf(at[r], fabsf(v1), sa1);
                sv0 = fmaf(at[r], vm, sv0); sa0 = fmaf(at[r], fabsf(vm), sa0);
                sv2 = fmaf(at[r], vp, sv2); sa2 = fmaf(at[r], fabsf(vp), sa2);
            }
        }
        // leaky = 0.6v + 0.4|v| factored; REDUCE ACROSS g-GROUPS (lanes
        // li, li+16, li+32, li+48 hold the same node's feature slices)
        float r0v = fmaf(0.6f, sv0, 0.4f * sa0);
        float r1v = fmaf(0.6f, sv1, 0.4f * sa1);
        float r2v = fmaf(0.6f, sv2, 0.4f * sa2);
        r0v += __shfl_xor(r0v, 16, 64); r0v += __shfl_xor(r0v, 32, 64);
        r1v += __shfl_xor(r1v, 16, 64); r1v += __shfl_xor(r1v, 32, 64);
        r2v += __shfl_xor(r2v, 16, 64); r2v += __shfl_xor(r2v, 32, 64);
        int node = mt * 16 + li;
        if (lane < 16 && node < NN) {
            float* row = &spart[wave][3 * node];
            if (li > 0)  row[0] = r0v;
            row[1] = r1v;
            if (li < 15) row[2] = r2v;
        }
    }

    // ---- boundary edges (cross 16-node tiles): mini edge-GEMM, 12 edges ----
    {
        int c = li;
        int s, d;
        if (c < 6)       { s = 16 * (c + 1) - 1; d = s + 1; }   // (15->16) etc
        else if (c < 12) { s = 16 * (c - 5);     d = s - 1; }   // (16->15) etc
        else             { s = 0; d = 0; }                       // pad, unread
        int slS = (s >> 4) * 128 + g * 16 + (s & 15);
        int slD = (d >> 4) * 128 + g * 16 + (d & 15);
        h8v e0 = sp[slS], e1 = sp[slS + 64];
        h8v e2 = sp[slD], e3 = sp[slD + 64];
        float sv = 0.f, sa = 0.f;
        #pragma unroll
        for (int j = 0; j < 2; ++j) {
            int feat = (nt0 + j) * 16 + g * 4;
            float4 ca = *(const float4*)&cadd[(0 * NN + s) * HH + feat];
            float4 cb = *(const float4*)&cadd[(1 * NN + d) * HH + feat];
            f4v c0;
            c0[0] = ca.x + cb.x; c0[1] = ca.y + cb.y;
            c0[2] = ca.z + cb.z; c0[3] = ca.w + cb.w;
            c0 = __builtin_amdgcn_mfma_f32_16x16x32_f16(wf[j][0][0], e0, c0, 0, 0, 0);
            c0 = __builtin_amdgcn_mfma_f32_16x16x32_f16(wf[j][0][1], e1, c0, 0, 0, 0);
            c0 = __builtin_amdgcn_mfma_f32_16x16x32_f16(wf[j][1][0], e2, c0, 0, 0, 0);
            c0 = __builtin_amdgcn_mfma_f32_16x16x32_f16(wf[j][1][1], e3, c0, 0, 0, 0);
            f4v at = j ? aB : aA;
            #pragma unroll
            for (int r = 0; r < 4; ++r) {
                sv = fmaf(at[r], c0[r], sv);
                sa = fmaf(at[r], fabsf(c0[r]), sa);
            }
        }
        float sb = fmaf(0.6f, sv, 0.4f * sa);
        sb += __shfl_xor(sb, 16, 64);
        sb += __shfl_xor(sb, 32, 64);          // sum over 4 feat-groups
        if (lane < 16) spartB[wave][lane] = sb;
    }
    __syncthreads();                           // spart/spartB done; sxs dead

    // scratch aliases sxs
    float* lg      = (float*)sxs;          // 304 floats
    float* wvp     = lg + 304;             // 100 floats
    float* partial = wvp + 108;            // 12 floats
    float* ypart   = partial + 16;         // 8*64 floats

    if (t < 300) {
        int q3 = t % 3, s = t / 3;
        int slot = -1;
        if (q3 == 2 && (s & 15) == 15)               slot = s >> 4;        // s->s+1
        else if (q3 == 0 && t > 0 && (s & 15) == 0)  slot = 5 + (s >> 4);  // s->s-1
        float v = 0.f;
        if (slot >= 0) {
            #pragma unroll
            for (int w = 0; w < 8; ++w) v += spartB[w][slot];
        } else {
            #pragma unroll
            for (int w = 0; w < 8; ++w) v += spart[w][t];
        }
        lg[t] = v;
    }
    __syncthreads();

    // ---- wv[i] = sum over dst j in {i-1,i,i+1} of alpha(i->j) ----
    if (t < NN) {
        int i = t;
        float w = 0.f;
        #pragma unroll
        for (int dj = -1; dj <= 1; ++dj) {
            int j = i + dj;
            if (j < 0 || j >= NN) continue;
            float l0 = (j - 1 >= 0) ? lg[3 * (j - 1) + 2] : -1e30f;  // j-1 -> j
            float l1 = lg[3 * j + 1];                                 // j   -> j
            float l2 = (j + 1 < NN) ? lg[3 * (j + 1) + 0] : -1e30f;  // j+1 -> j
            float mx = fmaxf(fmaxf(l0, l1), l2);
            float den = expf(l0 - mx) + expf(l1 - mx) + expf(l2 - mx);
            float myl = lg[3 * i + dj + 1];
            w += expf(myl - mx) / den;
        }
        wvp[i] = w;
    }
    __syncthreads();

    // ---- y[k] = sum_i wv[i] * x[b][i][k]  (k < 64), per-wave row chunks ----
    {
        int r0 = wave * 13;
        int r1 = (r0 + 13 < NN) ? r0 + 13 : NN;
        float acc = 0.f;
        for (int i = r0; i < r1; ++i)
            acc = fmaf(wvp[i], xb[i * INF_ + lane], acc);
        ypart[wave * 64 + lane] = acc;
    }
    __syncthreads();
    if (t < 64) {
        float s = 0.f;
        #pragma unroll
        for (int w = 0; w < 8; ++w) s += ypart[w * 64 + t];
        ypart[t] = s;                       // y[k]
    }
    __syncthreads();

    // ---- pooled[f] = y @ Wcomb_l[:,f] + wv @ cadd_l[:,f] + 100*bias[f]; FC ----
    if (t < HH) {
        float p = 100.f * bias[2 * HH + t];
        #pragma unroll
        for (int k = 0; k < INF_; k += 4) {
            float4 y4 = *(const float4*)&ypart[k];
            p = fmaf(y4.x, Wcomb[(k + 0) * HH + t], p);
            p = fmaf(y4.y, Wcomb[(k + 1) * HH + t], p);
            p = fmaf(y4.z, Wcomb[(k + 2) * HH + t], p);
            p = fmaf(y4.w, Wcomb[(k + 3) * HH + t], p);
        }
        #pragma unroll
        for (int i = 0; i < NN; i += 4) {
            float4 w4v = *(const float4*)&wvp[i];
            p = fmaf(w4v.x, cadd[(i + 0) * HH + t], p);
            p = fmaf(w4v.y, cadd[(i + 1) * HH + t], p);
            p = fmaf(w4v.z, cadd[(i + 2) * HH + t], p);
            p = fmaf(w4v.w, cadd[(i + 3) * HH + t], p);
        }

        float p0 = p * Wfc[t * 3 + 0];
        float p1 = p * Wfc[t * 3 + 1];
        float p2 = p * Wfc[t * 3 + 2];
        #pragma unroll
        for (int off = 32; off; off >>= 1) {
            p0 += __shfl_down(p0, off, 64);
            p1 += __shfl_down(p1, off, 64);
            p2 += __shfl_down(p2, off, 64);
        }
        if (lane == 0) {
            partial[wave * 3 + 0] = p0;
            partial[wave * 3 + 1] = p1;
            partial[wave * 3 + 2] = p2;
        }
    }
    __syncthreads();
    if (t < CC) {
        out[(size_t)b * CC + t] =
            partial[0 * 3 + t] + partial[1 * 3 + t] +
            partial[2 * 3 + t] + partial[3 * 3 + t] + bfc[t];
    }
}

// ---------------------------------------------------------------------------
extern "C" void kernel_launch(void* const* d_in, const int* in_sizes, int n_in,
                              void* d_out, int out_size, void* d_ws, size_t ws_size,
                              hipStream_t stream) {
    const float* x     = (const float*)d_in[0];
    const float* W_exp = (const float*)d_in[1];
    const float* b_exp = (const float*)d_in[2];
    const float* W_l   = (const float*)d_in[3];
    const float* b_l   = (const float*)d_in[4];
    const float* W_r   = (const float*)d_in[5];
    const float* b_r   = (const float*)d_in[6];
    const float* att   = (const float*)d_in[7];
    const float* bias  = (const float*)d_in[8];
    const float* W_fc  = (const float*)d_in[9];
    const float* b_fc  = (const float*)d_in[10];
    float* out = (float*)d_out;

    // workspace layout (16B aligned)
    char* ws = (char*)d_ws;
    float* Wcomb = (float*)ws;                                     // 131072 B
    float* cadd  = (float*)(ws + 131072);                          // 204800 B
    unsigned short* WF = (unsigned short*)(ws + 131072 + 204800);  // 65536 B
    float* CFf = (float*)(ws + 131072 + 204800 + 65536);           // 229376 B

    precompute_k<<<dim3(164, 2), 256, 0, stream>>>(W_exp, b_exp, W_l, b_l, W_r, b_r,
                                                   Wcomb, cadd);
    rearrange_k<<<184, 256, 0, stream>>>(Wcomb, cadd, WF, CFf);
    fused_k<<<BB, 512, 0, stream>>>(x, WF, CFf, Wcomb, cadd, att, bias, W_fc, b_fc, out);
}